// Round 13
// baseline (182.584 us; speedup 1.0000x reference)
//
#include <hip/hip_runtime.h>

#define CIN   64
#define COUT  128
#define HW    56
#define LTAPS 576   // CIN * 9

// ws layout: f32 scale @0; u8 G @256 (576*256*128 = 18,874,368 B);
//            i32 wT @ 256+18874368 (73728*4 B).
// G[l][a][co] u8: offset ((l*256 + a) << 7) + co   (row 128 B, tap slab 32 KB)

// ---------------------------------------------------------------------------
// Kernel 0: s = max|lut| / 127   (one 1024-thread block)
// ---------------------------------------------------------------------------
__global__ __launch_bounds__(1024) void lut_absmax(const float* __restrict__ lut,
                                                   float* __restrict__ ws_scale) {
    __shared__ float red[16];
    int tid = threadIdx.x;
    float m = 0.f;
    const float4* l4 = (const float4*)lut;
    for (int i = tid; i < 16384; i += 1024) {
        float4 v = l4[i];
        m = fmaxf(m, fmaxf(fmaxf(fabsf(v.x), fabsf(v.y)),
                           fmaxf(fabsf(v.z), fabsf(v.w))));
    }
    for (int off = 32; off > 0; off >>= 1)
        m = fmaxf(m, __shfl_down(m, off, 64));
    if ((tid & 63) == 0) red[tid >> 6] = m;
    __syncthreads();
    if (tid == 0) {
#pragma unroll
        for (int i = 1; i < 16; ++i) m = fmaxf(m, red[i]);
        ws_scale[0] = m / 127.0f;
    }
}

// ---------------------------------------------------------------------------
// Kernel 0b: wT[l*128 + co] = weight[co*576 + l]  (coalesced writes)
// ---------------------------------------------------------------------------
__global__ __launch_bounds__(256) void transpose_w(const int* __restrict__ weight,
                                                   int* __restrict__ wT) {
    int idx = blockIdx.x * 256 + threadIdx.x;   // 73728 total
    wT[idx] = weight[(idx & 127) * LTAPS + (idx >> 7)];
}

// ---------------------------------------------------------------------------
// Kernel 1: build u8 G from wT (coalesced): q = rint(lut[a,w]/s) + 128
// ---------------------------------------------------------------------------
__global__ __launch_bounds__(256) void build_G8(const int* __restrict__ wT,
                                                const float* __restrict__ lut,
                                                const float* __restrict__ ws_scale,
                                                uint2* __restrict__ G) {
    int idx = blockIdx.x * 256 + threadIdx.x;   // (l*256 + a)*16 + c8
    int c8 = idx & 15;
    int la = idx >> 4;
    int a  = la & 255;
    int l  = la >> 8;
    int co = c8 * 8;
    float inv = 1.0f / ws_scale[0];
    const float* lr = lut + a * 256;
    const int*   wr = wT + l * 128 + co;
    int4 wa = *(const int4*)wr;
    int4 wb = *(const int4*)(wr + 4);
    int w[8] = {wa.x, wa.y, wa.z, wa.w, wb.x, wb.y, wb.z, wb.w};
    unsigned int p0 = 0, p1 = 0;
#pragma unroll
    for (int j = 0; j < 4; ++j) {
        int qv = (int)rintf(lr[w[j]] * inv) + 128;
        qv = qv < 0 ? 0 : (qv > 255 ? 255 : qv);
        p0 |= (unsigned int)qv << (8 * j);
    }
#pragma unroll
    for (int j = 0; j < 4; ++j) {
        int qv = (int)rintf(lr[w[4 + j]] * inv) + 128;
        qv = qv < 0 ? 0 : (qv > 255 ? 255 : qv);
        p1 |= (unsigned int)qv << (8 * j);
    }
    uint2 v; v.x = p0; v.y = p1;
    G[idx] = v;
}

// ---------------------------------------------------------------------------
// Kernel 2: main conv -- DISCRIMINATING EXPERIMENT for the 15.7 TB/s plateau.
// 3136 blocks x 128 threads (2 waves/block, 24.5 waves/CU -- 2x rounds 11/12)
// with the SAME total load count (115M uint4) and same VALU/byte: each wave
// handles HALF the ci range (h = ci-half), combined via LDS at the end.
//   q = tid & 7        -> co = 16q..16q+15 (16 B uint4 of the 128 B row)
//   h = (tid >> 3) & 1 -> ci in [32h, 32h+32)
//   g = tid >> 4       -> pixel 0..7 (2 rows x 4 cols tile)
// If time drops to ~90 us -> overlap-limited (more waves fixed it).
// If time stays ~117 us -> random-line L2 ceiling; declare roofline.
// NO launch_bounds min-waves hint (r7/r10: caps -> scratch spill).
// ---------------------------------------------------------------------------

#if __has_builtin(__builtin_amdgcn_perm)
#define ODDB(w) __builtin_amdgcn_perm(0u, (w), 0x0C030C01u)  // {0,b3,0,b1}
#else
#define ODDB(w) (((w) >> 8) & 0x00FF00FFu)
#endif

#define MACC4(w, L, H)  L += (w) & 0x00FF00FFu;  H += ODDB(w);

#define MACC16(d)                                                              \
    MACC4((d).x, aL0, aH0) MACC4((d).y, aL1, aH1)                              \
    MACC4((d).z, aL2, aH2) MACC4((d).w, aL3, aH3)

#define DECL3(p) uint4 p##0, p##1, p##2;

#define PF3(p, ci, ky)                                                         \
    {                                                                          \
        const unsigned char* sc = sA + (ci) * 24 + pb + (ky) * 6;              \
        const unsigned char* Gl = Gq + ((size_t)((ci) * 9 + (ky) * 3) << 15);  \
        p##0 = *(const uint4*)(Gl + (0 << 15) + ((int)sc[0] << 7));            \
        p##1 = *(const uint4*)(Gl + (1 << 15) + ((int)sc[1] << 7));            \
        p##2 = *(const uint4*)(Gl + (2 << 15) + ((int)sc[2] << 7));            \
    }

#define CS3(p) MACC16(p##0) MACC16(p##1) MACC16(p##2)

#define FLUSH16                                                                \
    A0  += aL0 & 0xFFFFu;  A2  += aL0 >> 16;                                   \
    A1  += aH0 & 0xFFFFu;  A3  += aH0 >> 16;                                   \
    A4  += aL1 & 0xFFFFu;  A6  += aL1 >> 16;                                   \
    A5  += aH1 & 0xFFFFu;  A7  += aH1 >> 16;                                   \
    A8  += aL2 & 0xFFFFu;  A10 += aL2 >> 16;                                   \
    A9  += aH2 & 0xFFFFu;  A11 += aH2 >> 16;                                   \
    A12 += aL3 & 0xFFFFu;  A14 += aL3 >> 16;                                   \
    A13 += aH3 & 0xFFFFu;  A15 += aH3 >> 16;                                   \
    aL0 = aL1 = aL2 = aL3 = 0u; aH0 = aH1 = aH2 = aH3 = 0u;

__global__ __launch_bounds__(128) void conv_i8(const int* __restrict__ input,
                                               const unsigned char* __restrict__ G,
                                               const float* __restrict__ bias,
                                               const float* __restrict__ ws_scale,
                                               float* __restrict__ out) {
    __shared__ unsigned int smem[1024];            // 4 KB: sA (1536 B) then reduce
    unsigned char* sA = (unsigned char*)smem;      // [ci][4][6] halo of 2x4 tile

    int bx = blockIdx.x;
    int b  = bx / 392;          // 392 = 28*14 tiles per image (2 rows x 4 cols)
    int r  = bx % 392;
    int y0 = (r / 14) * 2;
    int x0 = (r % 14) * 4;

    int tid = threadIdx.x;

    // ---- stage 4x6 patch codes per ci (zero-pad = code 0) ----
    for (int i = tid; i < CIN * 24; i += 128) {
        int ci = i / 24, rr = i % 24;
        int yy = y0 + rr / 6 - 1;
        int xx = x0 + rr % 6 - 1;
        int v = 0;
        if (yy >= 0 && yy < HW && xx >= 0 && xx < HW)
            v = input[((b * CIN + ci) * HW + yy) * HW + xx];
        sA[i] = (unsigned char)v;
    }
    __syncthreads();

    const int q  = tid & 7;             // co 16-group
    const int h  = (tid >> 3) & 1;      // ci half
    const int g  = tid >> 4;            // pixel 0..7
    const int py = g >> 2, px = g & 3;  // 2 rows x 4 cols
    const int pb = py * 6 + px;
    const unsigned char* Gq = G + q * 16;
    const int cb = h * 32;

    unsigned int A0  = 0, A1  = 0, A2  = 0, A3  = 0;
    unsigned int A4  = 0, A5  = 0, A6  = 0, A7  = 0;
    unsigned int A8  = 0, A9  = 0, A10 = 0, A11 = 0;
    unsigned int A12 = 0, A13 = 0, A14 = 0, A15 = 0;
    unsigned int aL0 = 0, aL1 = 0, aL2 = 0, aL3 = 0;
    unsigned int aH0 = 0, aH1 = 0, aH2 = 0, aH3 = 0;

    DECL3(u)
    DECL3(v)
    PF3(u, cb, 0);

    for (int c2 = 0; c2 < 32; c2 += 2) {
        const int ci = cb + c2;
        PF3(v, ci, 1);       CS3(u)
        PF3(u, ci, 2);       CS3(v)
        PF3(v, ci + 1, 0);   CS3(u)
        PF3(u, ci + 1, 1);   CS3(v)
        PF3(v, ci + 1, 2);   CS3(u)
        if (c2 + 2 < 32) { PF3(u, cb + c2 + 2, 0); }
        CS3(v)
        if (((c2 + 2) & 15) == 0) { FLUSH16 }       // after 16 and 32 ci
    }

    // ---- combine ci halves via LDS (reuse smem after barrier) ----
    const int pidx = (g << 3) | q;      // 0..63
    __syncthreads();                    // all sA reads done
    if (h) {
        unsigned int* dst = smem + pidx * 16;
        dst[0]  = A0;  dst[1]  = A1;  dst[2]  = A2;  dst[3]  = A3;
        dst[4]  = A4;  dst[5]  = A5;  dst[6]  = A6;  dst[7]  = A7;
        dst[8]  = A8;  dst[9]  = A9;  dst[10] = A10; dst[11] = A11;
        dst[12] = A12; dst[13] = A13; dst[14] = A14; dst[15] = A15;
    }
    __syncthreads();
    if (!h) {
        const unsigned int* src = smem + pidx * 16;
        A0  += src[0];  A1  += src[1];  A2  += src[2];  A3  += src[3];
        A4  += src[4];  A5  += src[5];  A6  += src[6];  A7  += src[7];
        A8  += src[8];  A9  += src[9];  A10 += src[10]; A11 += src[11];
        A12 += src[12]; A13 += src[13]; A14 += src[14]; A15 += src[15];

        const float s   = ws_scale[0];
        const int   oh  = y0 + py, ow = x0 + px;
        const int   cob = q * 16;
        const float* bb = bias + cob;
        float* ob = out + (size_t)(b * COUT + cob) * (HW * HW)
                        + (size_t)oh * HW + ow;
        ob[0  * HW * HW] = s * (float)((int)A0  - 73728) + bb[0];
        ob[1  * HW * HW] = s * (float)((int)A1  - 73728) + bb[1];
        ob[2  * HW * HW] = s * (float)((int)A2  - 73728) + bb[2];
        ob[3  * HW * HW] = s * (float)((int)A3  - 73728) + bb[3];
        ob[4  * HW * HW] = s * (float)((int)A4  - 73728) + bb[4];
        ob[5  * HW * HW] = s * (float)((int)A5  - 73728) + bb[5];
        ob[6  * HW * HW] = s * (float)((int)A6  - 73728) + bb[6];
        ob[7  * HW * HW] = s * (float)((int)A7  - 73728) + bb[7];
        ob[8  * HW * HW] = s * (float)((int)A8  - 73728) + bb[8];
        ob[9  * HW * HW] = s * (float)((int)A9  - 73728) + bb[9];
        ob[10 * HW * HW] = s * (float)((int)A10 - 73728) + bb[10];
        ob[11 * HW * HW] = s * (float)((int)A11 - 73728) + bb[11];
        ob[12 * HW * HW] = s * (float)((int)A12 - 73728) + bb[12];
        ob[13 * HW * HW] = s * (float)((int)A13 - 73728) + bb[13];
        ob[14 * HW * HW] = s * (float)((int)A14 - 73728) + bb[14];
        ob[15 * HW * HW] = s * (float)((int)A15 - 73728) + bb[15];
    }
}

// ---------------------------------------------------------------------------
// Fallback (ws too small): gather lut directly, fp32 exact. 4x4 tiles.
// ---------------------------------------------------------------------------
__global__ __launch_bounds__(256) void conv_direct(const int* __restrict__ input,
                                                   const int* __restrict__ weight,
                                                   const float* __restrict__ lut,
                                                   const float* __restrict__ bias,
                                                   float* __restrict__ out) {
    __shared__ unsigned char sA[CIN * 36];

    int bx = blockIdx.x;
    int b  = bx / 196;
    int r  = bx % 196;
    int y0 = (r / 14) * 4;
    int x0 = (r % 14) * 4;

    int tid = threadIdx.x;
    for (int i = tid; i < CIN * 36; i += 256) {
        int ci = i / 36, rr = i % 36;
        int yy = y0 + rr / 6 - 1;
        int xx = x0 + rr % 6 - 1;
        int v = 0;
        if (yy >= 0 && yy < HW && xx >= 0 && xx < HW)
            v = input[((b * CIN + ci) * HW + yy) * HW + xx];
        sA[i] = (unsigned char)v;
    }
    __syncthreads();

    const int q  = tid & 31;
    const int g  = tid >> 5;
    const int qv = q * 4;
    const int p0 = g * 2, p1 = p0 + 1;
    const int py0 = p0 >> 2, px0 = p0 & 3;
    const int py1 = p1 >> 2, px1 = p1 & 3;
    const int pb0 = py0 * 6 + px0;
    const int pb1 = py1 * 6 + px1;

    float acc0[4] = {0.f, 0.f, 0.f, 0.f};
    float acc1[4] = {0.f, 0.f, 0.f, 0.f};
    const int off[9] = {0, 1, 2, 6, 7, 8, 12, 13, 14};

    for (int ci = 0; ci < CIN; ++ci) {
        const int cbase = ci * 36;
#pragma unroll
        for (int t = 0; t < 9; ++t) {
            const int l = ci * 9 + t;
            const int a0 = sA[cbase + pb0 + off[t]];
            const int a1 = sA[cbase + pb1 + off[t]];
#pragma unroll
            for (int j = 0; j < 4; ++j) {
                const int w = weight[(qv + j) * LTAPS + l];
                acc0[j] += lut[a0 * 256 + w];
                acc1[j] += lut[a1 * 256 + w];
            }
        }
    }

    const int oh0 = y0 + py0, ow0 = x0 + px0;
    const int oh1 = y0 + py1, ow1 = x0 + px1;
#pragma unroll
    for (int j = 0; j < 4; ++j) {
        const int co = qv + j;
        const float bb = bias[co];
        out[((size_t)(b * COUT + co) * HW + oh0) * HW + ow0] = acc0[j] + bb;
        out[((size_t)(b * COUT + co) * HW + oh1) * HW + ow1] = acc1[j] + bb;
    }
}

// ---------------------------------------------------------------------------
extern "C" void kernel_launch(void* const* d_in, const int* in_sizes, int n_in,
                              void* d_out, int out_size, void* d_ws, size_t ws_size,
                              hipStream_t stream) {
    const int*   input  = (const int*)d_in[0];
    const int*   weight = (const int*)d_in[1];
    const float* lut    = (const float*)d_in[2];
    const float* bias   = (const float*)d_in[3];
    float*       out    = (float*)d_out;

    const size_t g_off  = 256;
    const size_t g_size = (size_t)LTAPS * 256 * 128;        // 18,874,368
    const size_t w_off  = g_off + g_size;
    const size_t need   = w_off + (size_t)LTAPS * 128 * 4;  // + wT

    if (ws_size >= need) {
        float*         ws_scale = (float*)d_ws;
        unsigned char* G        = (unsigned char*)d_ws + g_off;
        int*           wT       = (int*)((unsigned char*)d_ws + w_off);
        lut_absmax<<<1, 1024, 0, stream>>>(lut, ws_scale);
        transpose_w<<<LTAPS * 128 / 256, 256, 0, stream>>>(weight, wT);
        build_G8<<<LTAPS * 16, 256, 0, stream>>>(wT, lut, ws_scale, (uint2*)G);
        conv_i8<<<8 * 392, 128, 0, stream>>>(input, G, bias, ws_scale, out);
    } else {
        conv_direct<<<8 * 196, 256, 0, stream>>>(input, weight, lut, bias, out);
    }
}

// Round 14
// 141.864 us; speedup vs baseline: 1.2870x; 1.2870x over previous
//
#include <hip/hip_runtime.h>

#define CIN   64
#define COUT  128
#define HW    56
#define LTAPS 576   // CIN * 9

// ws layout: f32 scale @0; u8 G @256 (576*256*128 = 18,874,368 B);
//            u8 luqT @ 256+18874368 (65536 B, transposed quantized lut).
// G[l][a][co] u8: offset ((l*256 + a) << 7) + co   (row 128 B, tap slab 32 KB)

// ---------------------------------------------------------------------------
// Kernel 0: s = max|lut| / 127   (one 1024-thread block)
// ---------------------------------------------------------------------------
__global__ __launch_bounds__(1024) void lut_absmax(const float* __restrict__ lut,
                                                   float* __restrict__ ws_scale) {
    __shared__ float red[16];
    int tid = threadIdx.x;
    float m = 0.f;
    const float4* l4 = (const float4*)lut;
    for (int i = tid; i < 16384; i += 1024) {
        float4 v = l4[i];
        m = fmaxf(m, fmaxf(fmaxf(fabsf(v.x), fabsf(v.y)),
                           fmaxf(fabsf(v.z), fabsf(v.w))));
    }
    for (int off = 32; off > 0; off >>= 1)
        m = fmaxf(m, __shfl_down(m, off, 64));
    if ((tid & 63) == 0) red[tid >> 6] = m;
    __syncthreads();
    if (tid == 0) {
#pragma unroll
        for (int i = 1; i < 16; ++i) m = fmaxf(m, red[i]);
        ws_scale[0] = m / 127.0f;
    }
}

// ---------------------------------------------------------------------------
// Kernel 1: luqT[w*256 + a] = clamp(rint(lut[a*256 + w]/s)) + 128  (u8,
// TRANSPOSED so the build kernel's LDS gathers are lane-consecutive).
// 64 blocks x 256 thr; idx = w*256 + a -> consecutive threads write
// consecutive a (coalesced stores); lut reads strided but tiny (256 KB).
// ---------------------------------------------------------------------------
__global__ __launch_bounds__(256) void quant_lutT(const float* __restrict__ lut,
                                                  const float* __restrict__ ws_scale,
                                                  unsigned char* __restrict__ luqT) {
    int idx = blockIdx.x * 256 + threadIdx.x;   // 65536 total
    int a = idx & 255;
    int w = idx >> 8;
    float inv = 1.0f / ws_scale[0];
    int qv = (int)rintf(lut[a * 256 + w] * inv) + 128;
    qv = qv < 0 ? 0 : (qv > 255 ? 255 : qv);
    luqT[idx] = (unsigned char)qv;
}

// ---------------------------------------------------------------------------
// Kernel 2: build G from LDS-staged luqT. One block per tap l (576 blocks).
// Stage all 64 KB of luqT in LDS + the 128 w codes for this tap; thread t
// emits G row a=t: for each co, byte = sluq[w[co]*256 + a] -- lane-consecutive
// LDS reads (conflict-free), packed to uint4, 16-B stores.
// Replaces the 18.9M random global 4-B gathers of the old build (TCP-bound
// ~20 us) with LDS gathers (~4 us).
// ---------------------------------------------------------------------------
__global__ __launch_bounds__(256) void build_G8_lds(const int* __restrict__ weight,
                                                    const unsigned char* __restrict__ luqT,
                                                    uint4* __restrict__ G) {
    __shared__ unsigned char sluq[65536];
    __shared__ int sw[128];

    const int l = blockIdx.x;
    const int tid = threadIdx.x;

    // stage luqT (16384 uint4 across 256 threads, coalesced)
    {
        uint4* d = (uint4*)sluq;
        const uint4* ssrc = (const uint4*)luqT;
        for (int i = tid; i < 4096; i += 256) d[i] = ssrc[i];
    }
    if (tid < 128) sw[tid] = weight[tid * LTAPS + l];
    __syncthreads();

    const int a = tid;
    uint4* grow = G + ((size_t)(l * 256 + a) << 3);   // row = 8 uint4
#pragma unroll
    for (int j = 0; j < 8; ++j) {
        unsigned int wds[4];
#pragma unroll
        for (int k = 0; k < 4; ++k) {
            const int cb = j * 16 + k * 4;
            unsigned int x = 0;
            x |= (unsigned int)sluq[sw[cb + 0] * 256 + a];
            x |= (unsigned int)sluq[sw[cb + 1] * 256 + a] << 8;
            x |= (unsigned int)sluq[sw[cb + 2] * 256 + a] << 16;
            x |= (unsigned int)sluq[sw[cb + 3] * 256 + a] << 24;
            wds[k] = x;
        }
        uint4 o; o.x = wds[0]; o.y = wds[1]; o.z = wds[2]; o.w = wds[3];
        grow[j] = o;
    }
}

// ---------------------------------------------------------------------------
// Kernel 3: main conv -- UNCHANGED from round 12 (at the random-line-service
// roofline: 28.9M 64-B lines at ~0.4-0.5 lines/cyc/CU ~= 117 us; verified
// invariant across fp16/u8, 1-6 waves/SIMD, 3 tile shapes, r2-r13).
// 3136 single-wave blocks; 2x4 px tile; q=tid&7 -> 16 co (uint4), g=tid>>3
// -> pixel; depth-6 ping-pong named regs; u16-field mask accumulate.
// ---------------------------------------------------------------------------

#if __has_builtin(__builtin_amdgcn_perm)
#define ODDB(w) __builtin_amdgcn_perm(0u, (w), 0x0C030C01u)  // {0,b3,0,b1}
#else
#define ODDB(w) (((w) >> 8) & 0x00FF00FFu)
#endif

#define MACC4(w, L, H)  L += (w) & 0x00FF00FFu;  H += ODDB(w);

#define MACC16(d)                                                              \
    MACC4((d).x, aL0, aH0) MACC4((d).y, aL1, aH1)                              \
    MACC4((d).z, aL2, aH2) MACC4((d).w, aL3, aH3)

#define DECL3(p) uint4 p##0, p##1, p##2;

#define PF3(p, ci, ky)                                                         \
    {                                                                          \
        const unsigned char* sc = sA + (ci) * 24 + pb + (ky) * 6;              \
        const unsigned char* Gl = Gq + ((size_t)((ci) * 9 + (ky) * 3) << 15);  \
        p##0 = *(const uint4*)(Gl + (0 << 15) + ((int)sc[0] << 7));            \
        p##1 = *(const uint4*)(Gl + (1 << 15) + ((int)sc[1] << 7));            \
        p##2 = *(const uint4*)(Gl + (2 << 15) + ((int)sc[2] << 7));            \
    }

#define CS3(p) MACC16(p##0) MACC16(p##1) MACC16(p##2)

#define FLUSH16                                                                \
    A0  += aL0 & 0xFFFFu;  A2  += aL0 >> 16;                                   \
    A1  += aH0 & 0xFFFFu;  A3  += aH0 >> 16;                                   \
    A4  += aL1 & 0xFFFFu;  A6  += aL1 >> 16;                                   \
    A5  += aH1 & 0xFFFFu;  A7  += aH1 >> 16;                                   \
    A8  += aL2 & 0xFFFFu;  A10 += aL2 >> 16;                                   \
    A9  += aH2 & 0xFFFFu;  A11 += aH2 >> 16;                                   \
    A12 += aL3 & 0xFFFFu;  A14 += aL3 >> 16;                                   \
    A13 += aH3 & 0xFFFFu;  A15 += aH3 >> 16;                                   \
    aL0 = aL1 = aL2 = aL3 = 0u; aH0 = aH1 = aH2 = aH3 = 0u;

__global__ __launch_bounds__(64) void conv_i8(const int* __restrict__ input,
                                              const unsigned char* __restrict__ G,
                                              const float* __restrict__ bias,
                                              const float* __restrict__ ws_scale,
                                              float* __restrict__ out) {
    __shared__ unsigned char sA[CIN * 24];   // [ci][4][6] halo of 2x4 tile

    int bx = blockIdx.x;
    int b  = bx / 392;          // 392 = 28*14 tiles per image (2 rows x 4 cols)
    int r  = bx % 392;
    int y0 = (r / 14) * 2;
    int x0 = (r % 14) * 4;

    int tid = threadIdx.x;

    // ---- stage 4x6 patch codes per ci (zero-pad = code 0) ----
    for (int i = tid; i < CIN * 24; i += 64) {
        int ci = i / 24, rr = i % 24;
        int yy = y0 + rr / 6 - 1;
        int xx = x0 + rr % 6 - 1;
        int v = 0;
        if (yy >= 0 && yy < HW && xx >= 0 && xx < HW)
            v = input[((b * CIN + ci) * HW + yy) * HW + xx];
        sA[i] = (unsigned char)v;
    }
    __syncthreads();

    const int q  = tid & 7;             // co 16-group
    const int g  = tid >> 3;            // pixel 0..7
    const int py = g >> 2, px = g & 3;  // 2 rows x 4 cols
    const int pb = py * 6 + px;
    const unsigned char* Gq = G + q * 16;

    unsigned int A0  = 0, A1  = 0, A2  = 0, A3  = 0;
    unsigned int A4  = 0, A5  = 0, A6  = 0, A7  = 0;
    unsigned int A8  = 0, A9  = 0, A10 = 0, A11 = 0;
    unsigned int A12 = 0, A13 = 0, A14 = 0, A15 = 0;
    unsigned int aL0 = 0, aL1 = 0, aL2 = 0, aL3 = 0;
    unsigned int aH0 = 0, aH1 = 0, aH2 = 0, aH3 = 0;

    DECL3(u)
    DECL3(v)
    PF3(u, 0, 0);

    for (int ci0 = 0; ci0 < CIN; ci0 += 2) {
        PF3(v, ci0, 1);       CS3(u)
        PF3(u, ci0, 2);       CS3(v)
        PF3(v, ci0 + 1, 0);   CS3(u)
        PF3(u, ci0 + 1, 1);   CS3(v)
        PF3(v, ci0 + 1, 2);   CS3(u)
        if (ci0 + 2 < CIN) { PF3(u, ci0 + 2, 0); }
        CS3(v)
        if (((ci0 + 2) & 15) == 0) { FLUSH16 }      // after ci 16/32/48/64
    }

    // ---- epilogue: remove u8 bias, scale, add conv bias, store ----
    const float s   = ws_scale[0];
    const int   oh  = y0 + py, ow = x0 + px;
    const int   cob = q * 16;
    const float* bb = bias + cob;
    float* ob = out + (size_t)(b * COUT + cob) * (HW * HW)
                    + (size_t)oh * HW + ow;
    ob[0  * HW * HW] = s * (float)((int)A0  - 73728) + bb[0];
    ob[1  * HW * HW] = s * (float)((int)A1  - 73728) + bb[1];
    ob[2  * HW * HW] = s * (float)((int)A2  - 73728) + bb[2];
    ob[3  * HW * HW] = s * (float)((int)A3  - 73728) + bb[3];
    ob[4  * HW * HW] = s * (float)((int)A4  - 73728) + bb[4];
    ob[5  * HW * HW] = s * (float)((int)A5  - 73728) + bb[5];
    ob[6  * HW * HW] = s * (float)((int)A6  - 73728) + bb[6];
    ob[7  * HW * HW] = s * (float)((int)A7  - 73728) + bb[7];
    ob[8  * HW * HW] = s * (float)((int)A8  - 73728) + bb[8];
    ob[9  * HW * HW] = s * (float)((int)A9  - 73728) + bb[9];
    ob[10 * HW * HW] = s * (float)((int)A10 - 73728) + bb[10];
    ob[11 * HW * HW] = s * (float)((int)A11 - 73728) + bb[11];
    ob[12 * HW * HW] = s * (float)((int)A12 - 73728) + bb[12];
    ob[13 * HW * HW] = s * (float)((int)A13 - 73728) + bb[13];
    ob[14 * HW * HW] = s * (float)((int)A14 - 73728) + bb[14];
    ob[15 * HW * HW] = s * (float)((int)A15 - 73728) + bb[15];
}

// ---------------------------------------------------------------------------
// Fallback (ws too small): gather lut directly, fp32 exact. 4x4 tiles.
// ---------------------------------------------------------------------------
__global__ __launch_bounds__(256) void conv_direct(const int* __restrict__ input,
                                                   const int* __restrict__ weight,
                                                   const float* __restrict__ lut,
                                                   const float* __restrict__ bias,
                                                   float* __restrict__ out) {
    __shared__ unsigned char sA[CIN * 36];

    int bx = blockIdx.x;
    int b  = bx / 196;
    int r  = bx % 196;
    int y0 = (r / 14) * 4;
    int x0 = (r % 14) * 4;

    int tid = threadIdx.x;
    for (int i = tid; i < CIN * 36; i += 256) {
        int ci = i / 36, rr = i % 36;
        int yy = y0 + rr / 6 - 1;
        int xx = x0 + rr % 6 - 1;
        int v = 0;
        if (yy >= 0 && yy < HW && xx >= 0 && xx < HW)
            v = input[((b * CIN + ci) * HW + yy) * HW + xx];
        sA[i] = (unsigned char)v;
    }
    __syncthreads();

    const int q  = tid & 31;
    const int g  = tid >> 5;
    const int qv = q * 4;
    const int p0 = g * 2, p1 = p0 + 1;
    const int py0 = p0 >> 2, px0 = p0 & 3;
    const int py1 = p1 >> 2, px1 = p1 & 3;
    const int pb0 = py0 * 6 + px0;
    const int pb1 = py1 * 6 + px1;

    float acc0[4] = {0.f, 0.f, 0.f, 0.f};
    float acc1[4] = {0.f, 0.f, 0.f, 0.f};
    const int off[9] = {0, 1, 2, 6, 7, 8, 12, 13, 14};

    for (int ci = 0; ci < CIN; ++ci) {
        const int cbase = ci * 36;
#pragma unroll
        for (int t = 0; t < 9; ++t) {
            const int l = ci * 9 + t;
            const int a0 = sA[cbase + pb0 + off[t]];
            const int a1 = sA[cbase + pb1 + off[t]];
#pragma unroll
            for (int j = 0; j < 4; ++j) {
                const int w = weight[(qv + j) * LTAPS + l];
                acc0[j] += lut[a0 * 256 + w];
                acc1[j] += lut[a1 * 256 + w];
            }
        }
    }

    const int oh0 = y0 + py0, ow0 = x0 + px0;
    const int oh1 = y0 + py1, ow1 = x0 + px1;
#pragma unroll
    for (int j = 0; j < 4; ++j) {
        const int co = qv + j;
        const float bb = bias[co];
        out[((size_t)(b * COUT + co) * HW + oh0) * HW + ow0] = acc0[j] + bb;
        out[((size_t)(b * COUT + co) * HW + oh1) * HW + ow1] = acc1[j] + bb;
    }
}

// ---------------------------------------------------------------------------
extern "C" void kernel_launch(void* const* d_in, const int* in_sizes, int n_in,
                              void* d_out, int out_size, void* d_ws, size_t ws_size,
                              hipStream_t stream) {
    const int*   input  = (const int*)d_in[0];
    const int*   weight = (const int*)d_in[1];
    const float* lut    = (const float*)d_in[2];
    const float* bias   = (const float*)d_in[3];
    float*       out    = (float*)d_out;

    const size_t g_off  = 256;
    const size_t g_size = (size_t)LTAPS * 256 * 128;        // 18,874,368
    const size_t q_off  = g_off + g_size;
    const size_t need   = q_off + 65536;                    // + luqT

    if (ws_size >= need) {
        float*         ws_scale = (float*)d_ws;
        unsigned char* G        = (unsigned char*)d_ws + g_off;
        unsigned char* luqT     = (unsigned char*)d_ws + q_off;
        lut_absmax<<<1, 1024, 0, stream>>>(lut, ws_scale);
        quant_lutT<<<256, 256, 0, stream>>>(lut, ws_scale, luqT);
        build_G8_lds<<<LTAPS, 256, 0, stream>>>(weight, luqT, (uint4*)G);
        conv_i8<<<8 * 392, 64, 0, stream>>>(input, G, bias, ws_scale, out);
    } else {
        conv_direct<<<8 * 196, 256, 0, stream>>>(input, weight, lut, bias, out);
    }
}